// Round 17
// baseline (502.186 us; speedup 1.0000x reference)
//
#include <hip/hip_runtime.h>
#include <hip/hip_bf16.h>
#include <math.h>

// GETS calibrator: MoE-GCN. N nodes, E edges, C=64, F=512, FH=32, DH=16.
// R17: k_combo deg blocks batched 4096 edges/block (391 blocks = 1564 waves,
//      ~19% of slots) -- R16 used 1563 deg blocks = 6252 waves which filled the
//      whole machine with fabric-waiting waves, leaving no room for proj waves
//      (measured: fused time == serial sum). Same atomics, same math.

#define XD 160   // aggregated feature dim (Zt layout)
#define CC 64    // classes
#define NREP 8   // counter replicas
#define DEG_EDGES_PER_BLOCK 4096

typedef __attribute__((ext_vector_type(8))) short short8;
typedef __attribute__((ext_vector_type(4))) float f32x4;

static __device__ inline unsigned pk_bf16(float a, float b) {
  __hip_bfloat162 h;
  h.x = __float2bfloat16(a);
  h.y = __float2bfloat16(b);
  return *reinterpret_cast<unsigned*>(&h);
}
static __device__ inline unsigned short bf16u(float f) {
  __hip_bfloat16 h = __float2bfloat16(f);
  return *reinterpret_cast<unsigned short*>(&h);
}
static __device__ inline float bf_lo(unsigned u) {
  unsigned v = u << 16;
  return __builtin_bit_cast(float, v);
}
static __device__ inline float bf_hi(unsigned u) {
  unsigned v = u & 0xffff0000u;
  return __builtin_bit_cast(float, v);
}

// ---------------- k_combo: degree atomics (few, batched blocks) + MFMA projection --------
__global__ __launch_bounds__(256) void k_combo(
    const int* __restrict__ ei, int E,
    unsigned* __restrict__ cntP, int n,
    const float* __restrict__ feat, const unsigned short* __restrict__ Wb,
    const float* __restrict__ bf0, const float* __restrict__ bf2,
    const float* __restrict__ Wv4, const float* __restrict__ logits,
    unsigned* __restrict__ Xu, float* __restrict__ CFG,
    int nblk_deg, int nblk_proj) {
  int bid = blockIdx.x;
  // interleave deg blocks early among proj blocks at ratio 1:4
  int type, idx;
  int nmix = 5 * nblk_deg;              // pattern: [deg, proj, proj, proj, proj] x nblk_deg
  if (bid < nmix && (nblk_proj >= 4 * nblk_deg)) {
    if ((bid % 5) == 0) { type = 0; idx = bid / 5; }
    else                { type = 1; idx = (bid / 5) * 4 + (bid % 5) - 1; }
  } else if (nblk_proj >= 4 * nblk_deg) {
    type = 1; idx = 4 * nblk_deg + (bid - nmix);
  } else {
    // fallback simple split
    if (bid < nblk_deg) { type = 0; idx = bid; }
    else                { type = 1; idx = bid - nblk_deg; }
  }

  if (type == 0) {
    // ---------- degree counting: 4096 edges per block, 16 per thread ----------
    int t = threadIdx.x;
    unsigned r = t & (NREP - 1);
    int base = idx * DEG_EDGES_PER_BLOCK;
#pragma unroll
    for (int q = 0; q < 16; ++q) {
      int e = base + q * 256 + t;
      if (e < E) {
        int s = ei[e], d = ei[E + e];
        atomicAdd(&cntP[r * (size_t)n + d], 1u);        // indeg
        atomicAdd(&cntP[r * (size_t)n + s], 0x10000u);  // outdeg
      }
    }
    return;
  }

  // ---------- projection (per-wave, identical math to R15/R16) ----------
  int l = threadIdx.x & 63;
  int wv = threadIdx.x >> 6;
  int gw = idx * 4 + wv;
  int node_in = gw * 16 + (l & 15);
  int nc = node_in < n ? node_in : n - 1;
  const float* frow = feat + (size_t)nc * 512 + ((l >> 4) << 3);

  f32x4 acc[4];
#pragma unroll
  for (int q = 0; q < 4; ++q) acc[q] = (f32x4){0.f, 0.f, 0.f, 0.f};
  float cfg0 = 0.f, cfg1 = 0.f, cfg2 = 0.f;

  for (int ks = 0; ks < 16; ++ks) {
    float4 fa = *(const float4*)&frow[ks * 32];
    float4 fb = *(const float4*)&frow[ks * 32 + 4];
    float fv[8] = {fa.x, fa.y, fa.z, fa.w, fb.x, fb.y, fb.z, fb.w};
    const float* wvp = Wv4 + (ks * 32 + ((l >> 4) << 3)) * 4;
#pragma unroll
    for (int j = 0; j < 8; ++j) {
      float4 v = *(const float4*)&wvp[j * 4];
      cfg0 += fv[j] * v.x;
      cfg1 += fv[j] * v.y;
      cfg2 += fv[j] * v.z;
    }
    unsigned short pa[8];
#pragma unroll
    for (int j = 0; j < 8; ++j) pa[j] = bf16u(fv[j]);
    short8 af = *(const short8*)pa;
#pragma unroll
    for (int nt = 0; nt < 4; ++nt) {
      short8 bfv = *(const short8*)&Wb[(size_t)((ks * 4 + nt) * 64 + l) * 8];
      acc[nt] = __builtin_amdgcn_mfma_f32_16x16x32_bf16(af, bfv, acc[nt], 0, 0, 0);
    }
  }

  cfg0 += __shfl_xor(cfg0, 16); cfg0 += __shfl_xor(cfg0, 32);
  cfg1 += __shfl_xor(cfg1, 16); cfg1 += __shfl_xor(cfg1, 32);
  cfg2 += __shfl_xor(cfg2, 16); cfg2 += __shfl_xor(cfg2, 32);
  if (l < 16 && node_in < n) {
    float4 cc = *(const float4*)&Wv4[512 * 4];
    CFG[node_in] = cfg0 + cc.x;
    CFG[n + node_in] = cfg1 + cc.y;
    CFG[2 * (size_t)n + node_in] = cfg2 + cc.z;
  }

  unsigned short* Xus = (unsigned short*)Xu;
#pragma unroll
  for (int nt = 0; nt < 4; ++nt) {
    int col = (nt << 4) + (l & 15);
    float bias = (col < 32) ? bf0[col] : bf2[col - 32];
    int fidx = 64 + col;
#pragma unroll
    for (int r = 0; r < 4; ++r) {
      int nd = gw * 16 + ((l >> 4) << 2) + r;
      if (nd < n) Xus[(size_t)nd * 128 + fidx] = bf16u(acc[nt][r] + bias);
    }
  }

  // ---------- logits -> Xu bf16 pack for this wave's 16 nodes ----------
  int nb16 = gw * 16;
#pragma unroll
  for (int q = 0; q < 8; ++q) {
    int ii = q * 64 + l;
    int nd = nb16 + (ii >> 5);
    int p = ii & 31;
    if (nd < n) {
      float2 lg = *(const float2*)&logits[(size_t)nd * 64 + 2 * p];
      Xu[(size_t)nd * 64 + p] = pk_bf16(lg.x, lg.y);
    }
  }
}

// ---------------- 2-level exclusive scan of indeg -> row_start ----------------
__global__ void k_scan1(const unsigned* __restrict__ cntP, int n, int* __restrict__ bsum) {
  __shared__ int red[1024];
  int tid = threadIdx.x;
  int i = blockIdx.x * 1024 + tid;
  int v = 0;
  if (i < n) {
    unsigned t = 0;
#pragma unroll
    for (int r = 0; r < NREP; ++r) t += cntP[r * (size_t)n + i];
    v = (int)(t & 0xFFFFu);
  }
  red[tid] = v;
  __syncthreads();
  for (int s = 512; s > 0; s >>= 1) {
    if (tid < s) red[tid] += red[tid + s];
    __syncthreads();
  }
  if (tid == 0) bsum[blockIdx.x] = red[0];
}

__global__ void k_scan2(int* __restrict__ bsum, int nb, int* __restrict__ row_start, int n) {
  if (threadIdx.x == 0 && blockIdx.x == 0) {
    int run = 0;
    for (int b = 0; b < nb; ++b) { int t = bsum[b]; bsum[b] = run; run += t; }
    row_start[n] = run;   // == E
  }
}

__global__ void k_scan3(const unsigned* __restrict__ cntP, int n, const int* __restrict__ bsum,
                        int* __restrict__ row_start, float* __restrict__ dinv,
                        int* __restrict__ deg_i) {
  __shared__ int sc[1024];
  int tid = threadIdx.x;
  int i = blockIdx.x * 1024 + tid;
  int indeg = 0, total = 0;
  if (i < n) {
    unsigned t = 0;
#pragma unroll
    for (int r = 0; r < NREP; ++r) t += cntP[r * (size_t)n + i];
    indeg = (int)(t & 0xFFFFu);
    total = indeg + (int)(t >> 16);
  }
  sc[tid] = indeg;
  __syncthreads();
  for (int ofs = 1; ofs < 1024; ofs <<= 1) {
    int t = (tid >= ofs) ? sc[tid - ofs] : 0;
    __syncthreads();
    sc[tid] += t;
    __syncthreads();
  }
  if (i < n) {
    int incl = sc[tid];
    row_start[i] = incl - indeg + bsum[blockIdx.x];
    dinv[i] = rsqrtf((float)indeg + 1.0f);   // GCN deg = indeg + 1 (self loop)
    deg_i[i] = total;                        // embedding degree = indeg + outdeg
  }
}

// ---------------- CSR fill: (src | deg<<20, coef) per edge ----------------
__global__ void k_fill(const int* __restrict__ ei, int E, const int* __restrict__ row_start,
                       int* __restrict__ cursor, const float* __restrict__ dinv,
                       const int* __restrict__ deg_i, int2* __restrict__ ec) {
  int e = blockIdx.x * blockDim.x + threadIdx.x;
  if (e >= E) return;
  int s = ei[e], d = ei[E + e];
  int pos = row_start[d] + atomicAdd(&cursor[d], 1);
  int dg = deg_i[s]; if (dg > 127) dg = 127;
  int2 v;
  v.x = s | (dg << 20);
  v.y = __float_as_int(dinv[s] * dinv[d]);
  ec[pos] = v;
}

// ---------------- Wv = Wfg(512x32) @ wg[64:96] (3 cols), fp32 ----------------
__global__ void k_wv(const float* __restrict__ Wfg, const float* __restrict__ bfg,
                     const float* __restrict__ wg, float* __restrict__ Wv4) {
  int k = blockIdx.x * blockDim.x + threadIdx.x;
  if (k >= 512) return;
  float a0 = 0.f, a1 = 0.f, a2 = 0.f;
  for (int j = 0; j < 32; ++j) {
    float w = Wfg[k * 32 + j];
    a0 += w * wg[(64 + j) * 3 + 0];
    a1 += w * wg[(64 + j) * 3 + 1];
    a2 += w * wg[(64 + j) * 3 + 2];
  }
  float4 v; v.x = a0; v.y = a1; v.z = a2; v.w = 0.f;
  *(float4*)&Wv4[k * 4] = v;
  if (k == 0) {
    float c0 = 0.f, c1 = 0.f, c2 = 0.f;
    for (int j = 0; j < 32; ++j) {
      float b = bfg[j];
      c0 += b * wg[(64 + j) * 3 + 0];
      c1 += b * wg[(64 + j) * 3 + 1];
      c2 += b * wg[(64 + j) * 3 + 2];
    }
    float4 c; c.x = c0; c.y = c1; c.z = c2; c.w = 0.f;
    *(float4*)&Wv4[512 * 4] = c;
  }
}

// ---------------- k_wb: [Wf0|Wf2] -> bf16 fragment-ordered Wb ----------------
__global__ void k_wb(const float* __restrict__ Wf0, const float* __restrict__ Wf2,
                     unsigned short* __restrict__ Wb) {
  int tid = blockIdx.x * blockDim.x + threadIdx.x;   // 4096 threads
  if (tid >= 16 * 4 * 64) return;
  int l = tid & 63;
  int nt = (tid >> 6) & 3;
  int ks = tid >> 8;
  int col = (nt << 4) + (l & 15);
  int rowb = ks * 32 + ((l >> 4) << 3);
  const float* wsrc = (col < 32) ? (Wf0 + col) : (Wf2 + (col - 32));
  unsigned short pb[8];
#pragma unroll
  for (int j = 0; j < 8; ++j)
    pb[j] = bf16u(wsrc[(size_t)(rowb + j) * 32]);
  *(uint4*)&Wb[(size_t)tid * 8] = *(const uint4*)pb;
}

// ---------------- aggregation: Zt(bf16) = A_hat @ [Xu(256B rows) | Emb(packed deg)] ------
__global__ __launch_bounds__(256) void k_agg(
    const unsigned* __restrict__ Xu, unsigned* __restrict__ Ztu,
    const int* __restrict__ row_start, const int2* __restrict__ ec,
    const int* __restrict__ deg_i,
    const float* __restrict__ Emb1, const float* __restrict__ Emb2,
    const float* __restrict__ dinv, int n) {
  int w = threadIdx.x >> 6, l = threadIdx.x & 63;
  int node = blockIdx.x * 4 + w;
  if (node >= n) return;
  int beg = row_start[node], end = row_start[node + 1];

  const float* etab = (l < 8) ? (Emb1 + 2 * l) : (Emb2 + 2 * (l - 8));

  float ax = 0.f, ay = 0.f, bx = 0.f, by = 0.f;
  int i = beg;
  for (; i + 4 <= end; i += 4) {
    int2 e0 = ec[i];
    int2 e1 = ec[i + 1];
    int2 e2 = ec[i + 2];
    int2 e3 = ec[i + 3];
    unsigned u0 = Xu[(size_t)(e0.x & 0xFFFFF) * 64 + l];
    unsigned u1 = Xu[(size_t)(e1.x & 0xFFFFF) * 64 + l];
    unsigned u2 = Xu[(size_t)(e2.x & 0xFFFFF) * 64 + l];
    unsigned u3 = Xu[(size_t)(e3.x & 0xFFFFF) * 64 + l];
    float c0 = __int_as_float(e0.y);
    float c1 = __int_as_float(e1.y);
    float c2 = __int_as_float(e2.y);
    float c3 = __int_as_float(e3.y);
    ax += c0 * bf_lo(u0); ay += c0 * bf_hi(u0);
    ax += c1 * bf_lo(u1); ay += c1 * bf_hi(u1);
    ax += c2 * bf_lo(u2); ay += c2 * bf_hi(u2);
    ax += c3 * bf_lo(u3); ay += c3 * bf_hi(u3);
    if (l < 16) {
      float2 ev0 = *(const float2*)&etab[(e0.x >> 20) * 16];
      float2 ev1 = *(const float2*)&etab[(e1.x >> 20) * 16];
      float2 ev2 = *(const float2*)&etab[(e2.x >> 20) * 16];
      float2 ev3 = *(const float2*)&etab[(e3.x >> 20) * 16];
      bx += c0 * ev0.x; by += c0 * ev0.y;
      bx += c1 * ev1.x; by += c1 * ev1.y;
      bx += c2 * ev2.x; by += c2 * ev2.y;
      bx += c3 * ev3.x; by += c3 * ev3.y;
    }
  }
  for (; i < end; ++i) {
    int2 e0 = ec[i];
    int s0 = e0.x & 0xFFFFF;
    float c0 = __int_as_float(e0.y);
    unsigned u0 = Xu[(size_t)s0 * 64 + l];
    ax += c0 * bf_lo(u0); ay += c0 * bf_hi(u0);
    if (l < 16) {
      float2 ev0 = *(const float2*)&etab[(e0.x >> 20) * 16];
      bx += c0 * ev0.x; by += c0 * ev0.y;
    }
  }
  // self loop
  float di = dinv[node];
  float c2s = di * di;
  {
    unsigned u = Xu[(size_t)node * 64 + l];
    ax += c2s * bf_lo(u);
    ay += c2s * bf_hi(u);
    if (l < 16) {
      int dg = deg_i[node]; if (dg > 127) dg = 127;
      float2 ev = *(const float2*)&etab[dg * 16];
      bx += c2s * ev.x;
      by += c2s * ev.y;
    }
  }
  // main store: new feature nf=2l -> old feature (nf<96 ? nf : nf+16)
  {
    int nf = 2 * l;
    int of = nf + (nf >= 96 ? 16 : 0);
    Ztu[2 * ((size_t)(of >> 2) * n + node) + ((of >> 1) & 1)] = pk_bf16(ax, ay);
  }
  if (l < 16) {
    int p = l & 7;
    int of = (l < 8) ? (96 + 2 * p) : (144 + 2 * p);
    Ztu[2 * ((size_t)(of >> 2) * n + node) + (p & 1)] = pk_bf16(bx, by);
  }
}

// ---------------- final: 4-way column split, 1 wave/block, comb[16] ----------------
__global__ __launch_bounds__(64) void k_final(
    const unsigned* __restrict__ Ztu, const float* __restrict__ logits,
    const float* __restrict__ CFG, const int* __restrict__ deg_i,
    const float* __restrict__ W0, const float* __restrict__ b0,
    const float* __restrict__ W1, const float* __restrict__ b1,
    const float* __restrict__ W2, const float* __restrict__ b2,
    const float* __restrict__ Embg, const float* __restrict__ wg,
    float* __restrict__ out, int n) {
  int l = threadIdx.x;
  int g = blockIdx.x >> 2;
  int cb = (blockIdx.x & 3) * 16;      // column base
  int node = g * 64 + l;
  int nc = node < n ? node : n - 1;

  // ---- gating (fp32, full; identical in all 4 col-groups) ----
  float c0 = 0.f, c1 = 0.f, c2 = 0.f;
  const float* lgr = logits + (size_t)nc * 64;
#pragma unroll
  for (int q = 0; q < 16; ++q) {
    float4 v = *(const float4*)&lgr[q * 4];
    const float* p = (const float*)&v;
#pragma unroll
    for (int j = 0; j < 4; ++j) {
      int k = q * 4 + j;
      c0 += p[j] * wg[k * 3 + 0];
      c1 += p[j] * wg[k * 3 + 1];
      c2 += p[j] * wg[k * 3 + 2];
    }
  }
  {
    int dg = deg_i[nc]; if (dg > 127) dg = 127;
    const float* egr = Embg + dg * 16;
#pragma unroll
    for (int q = 0; q < 4; ++q) {
      float4 v = *(const float4*)&egr[q * 4];
      const float* p = (const float*)&v;
#pragma unroll
      for (int j = 0; j < 4; ++j) {
        int k = 96 + q * 4 + j;
        c0 += p[j] * wg[k * 3 + 0];
        c1 += p[j] * wg[k * 3 + 1];
        c2 += p[j] * wg[k * 3 + 2];
      }
    }
  }
  c0 += CFG[nc];
  c1 += CFG[n + nc];
  c2 += CFG[2 * (size_t)n + nc];

  int i0 = 0; float t0 = c0;
  if (c1 > t0) { t0 = c1; i0 = 1; }
  if (c2 > t0) { t0 = c2; i0 = 2; }
  float t1 = -3.4e38f; int i1 = 0;
  if (i0 != 0) { t1 = c0; i1 = 0; }
  if (i0 != 1 && c1 > t1) { t1 = c1; i1 = 1; }
  if (i0 != 2 && c2 > t1) { t1 = c2; i1 = 2; }
  float e1v = expf(t1 - t0);
  float gsum = 1.0f + e1v;
  float gA = 1.0f / gsum, gB = e1v / gsum;
  float g0 = (i0 == 0) ? gA : (i1 == 0) ? gB : 0.f;
  float g1 = (i0 == 1) ? gA : (i1 == 1) ? gB : 0.f;
  float g2 = (i0 == 2) ? gA : (i1 == 2) ? gB : 0.f;

  float comb[16];
#pragma unroll
  for (int c = 0; c < 16; ++c) comb[c] = 0.f;

#define CHUNK(CIDX, GE, WPTR, KROW)                                        \
  {                                                                        \
    uint2 zu = *(const uint2*)&Ztu[2 * ((size_t)(CIDX) * n + nc)];         \
    float zs[4] = {(GE) * bf_lo(zu.x), (GE) * bf_hi(zu.x),                 \
                   (GE) * bf_lo(zu.y), (GE) * bf_hi(zu.y)};                \
    const float* wr = (WPTR) + (KROW) * 64 + cb;                           \
    _Pragma("unroll") for (int kk = 0; kk < 4; ++kk) {                     \
      float zz = zs[kk];                                                   \
      const float* wrow = wr + kk * 64;                                    \
      _Pragma("unroll") for (int c = 0; c < 16; ++c)                       \
        comb[c] += zz * wrow[c];                                           \
    }                                                                      \
  }

  for (int t = 0; t < 24; ++t) CHUNK(t, g0, W0, 4 * t);
  for (int t = 0; t < 16; ++t) CHUNK(t, g1, W1, 4 * t);
  for (int t = 0; t < 4; ++t)  CHUNK(24 + t, g1, W1, 64 + 4 * t);
  for (int t = 0; t < 12; ++t) CHUNK(28 + t, g2, W2, 4 * t);
#undef CHUNK

#pragma unroll
  for (int c = 0; c < 16; ++c)
    comb[c] += g0 * b0[cb + c] + g1 * b1[cb + c] + g2 * b2[cb + c];

  if (node < n) {
    float* outr = out + (size_t)node * 64 + cb;
#pragma unroll
    for (int q = 0; q < 4; ++q) {
      float4 lg4 = *(const float4*)&lgr[cb + q * 4];
      const float* pl = (const float*)&lg4;
      float4 o;
      float* po = (float*)&o;
#pragma unroll
      for (int j = 0; j < 4; ++j) {
        float v = comb[q * 4 + j];
        float sp = fmaxf(v, 0.f) + log1pf(expf(-fabsf(v)));
        po[j] = pl[j] * sp;
      }
      *(float4*)&outr[q * 4] = o;
    }
  }
}

extern "C" void kernel_launch(void* const* d_in, const int* in_sizes, int n_in,
                              void* d_out, int out_size, void* d_ws, size_t ws_size,
                              hipStream_t stream) {
  const float* logits = (const float*)d_in[0];
  const float* feat   = (const float*)d_in[1];
  const int*   ei     = (const int*)d_in[2];
  const float* Wf0 = (const float*)d_in[3];
  const float* bf0 = (const float*)d_in[4];
  const float* W0  = (const float*)d_in[5];
  const float* b0  = (const float*)d_in[6];
  const float* Emb1= (const float*)d_in[7];
  const float* W1  = (const float*)d_in[8];
  const float* b1  = (const float*)d_in[9];
  const float* Wf2 = (const float*)d_in[10];
  const float* bf2 = (const float*)d_in[11];
  const float* Emb2= (const float*)d_in[12];
  const float* W2  = (const float*)d_in[13];
  const float* b2  = (const float*)d_in[14];
  const float* Wfg = (const float*)d_in[15];
  const float* bfg = (const float*)d_in[16];
  const float* Embg= (const float*)d_in[17];
  const float* wg  = (const float*)d_in[18];

  int n = in_sizes[0] / 64;
  int E = in_sizes[2] / 2;

  char* base = (char*)d_ws;
  size_t off = 0;
  auto alloc = [&](size_t bytes) -> void* {
    void* p = base + off;
    off += bytes;
    off = (off + 255) & ~(size_t)255;
    return p;
  };
  unsigned* cntP   = (unsigned*)alloc((size_t)NREP * n * 4);
  int*   cursor    = (int*)alloc((size_t)n * 4);
  size_t zero_bytes = off;                 // cntP + cursor
  int*   deg_i     = (int*)alloc((size_t)n * 4);
  int*   row_start = (int*)alloc(((size_t)n + 1) * 4);
  int*   bsum      = (int*)alloc(1024 * 4);
  float* dinv      = (float*)alloc((size_t)n * 4);
  int2*  ec        = (int2*)alloc((size_t)E * 8);
  float* CFG       = (float*)alloc((size_t)n * 3 * 4);
  float* Wv4       = (float*)alloc((size_t)513 * 4 * 4);
  unsigned short* Wb = (unsigned short*)alloc((size_t)16 * 4 * 64 * 8 * 2);  // 64KB
  unsigned* Xu     = (unsigned*)alloc((size_t)n * 64 * 4);   // bf16 X: 128 feat x 2B
  unsigned* Ztu    = (unsigned*)alloc((size_t)n * 80 * 4);   // bf16 Zt (160 feat)
  (void)ws_size;

  hipMemsetAsync(base, 0, zero_bytes, stream);

  int nb_scan = (n + 1023) / 1024;
  int nblk_deg  = (E + DEG_EDGES_PER_BLOCK - 1) / DEG_EDGES_PER_BLOCK;
  int nblk_proj = (n + 63) / 64;
  k_wv<<<2, 256, 0, stream>>>(Wfg, bfg, wg, Wv4);
  k_wb<<<16, 256, 0, stream>>>(Wf0, Wf2, Wb);
  k_combo<<<nblk_deg + nblk_proj, 256, 0, stream>>>(
      ei, E, cntP, n, feat, Wb, bf0, bf2, Wv4, logits, Xu, CFG,
      nblk_deg, nblk_proj);
  k_scan1<<<nb_scan, 1024, 0, stream>>>(cntP, n, bsum);
  k_scan2<<<1, 64, 0, stream>>>(bsum, nb_scan, row_start, n);
  k_scan3<<<nb_scan, 1024, 0, stream>>>(cntP, n, bsum, row_start, dinv, deg_i);
  k_fill<<<(E + 255) / 256, 256, 0, stream>>>(ei, E, row_start, cursor, dinv, deg_i, ec);
  k_agg<<<(n + 3) / 4, 256, 0, stream>>>(Xu, Ztu, row_start, ec, deg_i, Emb1, Emb2, dinv, n);
  int waves = (n + 63) / 64;
  k_final<<<waves * 4, 64, 0, stream>>>(Ztu, logits, CFG, deg_i, W0, b0, W1, b1, W2, b2,
                                        Embg, wg, (float*)d_out, n);
}

// Round 18
// 482.712 us; speedup vs baseline: 1.0403x; 1.0403x over previous
//
#include <hip/hip_runtime.h>
#include <hip/hip_bf16.h>
#include <math.h>

// GETS calibrator: MoE-GCN. N nodes, E edges, C=64, F=512, FH=32, DH=16.
// R18: degree counting rewritten as bucket partition (k_h0/k_hs/k_hb/k_h3):
//      per-edge global atomics eliminated (3.2M RMW @26G/s was a 122us floor and
//      poisoned all fusion overlap -- R16/R17). Only ~77k chunk-reservation
//      atomics + LDS atomics remain. k_projm de-fused back to standalone.

#define XD 160   // aggregated feature dim (Zt layout)
#define CC 64    // classes

typedef __attribute__((ext_vector_type(8))) short short8;
typedef __attribute__((ext_vector_type(4))) float f32x4;

static __device__ inline unsigned pk_bf16(float a, float b) {
  __hip_bfloat162 h;
  h.x = __float2bfloat16(a);
  h.y = __float2bfloat16(b);
  return *reinterpret_cast<unsigned*>(&h);
}
static __device__ inline unsigned short bf16u(float f) {
  __hip_bfloat16 h = __float2bfloat16(f);
  return *reinterpret_cast<unsigned short*>(&h);
}
static __device__ inline float bf_lo(unsigned u) {
  unsigned v = u << 16;
  return __builtin_bit_cast(float, v);
}
static __device__ inline float bf_hi(unsigned u) {
  unsigned v = u & 0xffff0000u;
  return __builtin_bit_cast(float, v);
}

// ================= degree build via bucket partition (no per-edge global atomics) ========
// Streams: ids idx in [0,E) are src (-> outdeg), [E,2E) are dst (-> indeg).
// bucket = stream*nbk + (v>>9); nbk = ceil(n/512) (n <= 131072 -> 2*nbk <= 512).

__global__ __launch_bounds__(256) void k_h0(const int* __restrict__ ei, int E2, int E,
                                            int nbk, unsigned* __restrict__ bucketTotal) {
  __shared__ int h[512];
  int t = threadIdx.x;
  int nb2 = 2 * nbk;
  for (int i = t; i < nb2; i += 256) h[i] = 0;
  __syncthreads();
  int base = blockIdx.x * 4096;
#pragma unroll
  for (int q = 0; q < 16; ++q) {
    int idx = base + q * 256 + t;
    if (idx < E2) {
      int v = ei[idx];
      int bk = (idx < E ? 0 : nbk) + (v >> 9);
      atomicAdd(&h[bk], 1);
    }
  }
  __syncthreads();
  for (int i = t; i < nb2; i += 256)
    if (h[i]) atomicAdd(&bucketTotal[i], (unsigned)h[i]);
}

__global__ void k_hs(const unsigned* __restrict__ bucketTotal, int nb2,
                     unsigned* __restrict__ bucketOffset, unsigned* __restrict__ bucketCursor) {
  if (threadIdx.x == 0 && blockIdx.x == 0) {
    unsigned run = 0;
    for (int i = 0; i < nb2; ++i) {
      bucketOffset[i] = run;
      bucketCursor[i] = run;
      run += bucketTotal[i];
    }
    bucketOffset[nb2] = run;
  }
}

__global__ __launch_bounds__(256) void k_hb(const int* __restrict__ ei, int E2, int E,
                                            int nbk, unsigned* __restrict__ bucketCursor,
                                            int* __restrict__ partIds) {
  __shared__ int h[512];
  __shared__ unsigned baseb[512];
  int t = threadIdx.x;
  int nb2 = 2 * nbk;
  for (int i = t; i < nb2; i += 256) h[i] = 0;
  __syncthreads();
  int base = blockIdx.x * 4096;
  int myv[16], mybk[16];
#pragma unroll
  for (int q = 0; q < 16; ++q) {
    int idx = base + q * 256 + t;
    if (idx < E2) {
      int v = ei[idx];
      int bk = (idx < E ? 0 : nbk) + (v >> 9);
      myv[q] = v; mybk[q] = bk;
      atomicAdd(&h[bk], 1);
    } else mybk[q] = -1;
  }
  __syncthreads();
  for (int i = t; i < nb2; i += 256)
    baseb[i] = h[i] ? atomicAdd(&bucketCursor[i], (unsigned)h[i]) : 0u;
  __syncthreads();
  for (int i = t; i < nb2; i += 256) h[i] = 0;
  __syncthreads();
#pragma unroll
  for (int q = 0; q < 16; ++q) {
    int bk = mybk[q];
    if (bk >= 0) {
      int r = atomicAdd(&h[bk], 1);
      partIds[baseb[bk] + r] = myv[q];
    }
  }
}

__global__ __launch_bounds__(256) void k_h3(const int* __restrict__ partIds,
                                            const unsigned* __restrict__ bucketOffset,
                                            int nbk, int n,
                                            int* __restrict__ indeg, int* __restrict__ outdeg) {
  __shared__ int cnt[512];
  int b = blockIdx.x;
  int t = threadIdx.x;
  for (int i = t; i < 512; i += 256) cnt[i] = 0;
  __syncthreads();
  unsigned s = bucketOffset[b], e = bucketOffset[b + 1];
  for (unsigned i = s + t; i < e; i += 256) {
    int v = partIds[i];
    atomicAdd(&cnt[v & 511], 1);
  }
  __syncthreads();
  int isDst = (b >= nbk);
  int nb = isDst ? (b - nbk) : b;
  int* dst = isDst ? indeg : outdeg;   // src-stream buckets -> outdeg
  for (int i = t; i < 512; i += 256) {
    int node = nb * 512 + i;
    if (node < n) dst[node] = cnt[i];
  }
}

// ---------------- 2-level exclusive scan of indeg -> row_start ----------------
__global__ void k_scan1(const int* __restrict__ indeg, int n, int* __restrict__ bsum) {
  __shared__ int red[1024];
  int tid = threadIdx.x;
  int i = blockIdx.x * 1024 + tid;
  red[tid] = (i < n) ? indeg[i] : 0;
  __syncthreads();
  for (int s = 512; s > 0; s >>= 1) {
    if (tid < s) red[tid] += red[tid + s];
    __syncthreads();
  }
  if (tid == 0) bsum[blockIdx.x] = red[0];
}

__global__ void k_scan2(int* __restrict__ bsum, int nb, int* __restrict__ row_start, int n) {
  if (threadIdx.x == 0 && blockIdx.x == 0) {
    int run = 0;
    for (int b = 0; b < nb; ++b) { int t = bsum[b]; bsum[b] = run; run += t; }
    row_start[n] = run;   // == E
  }
}

__global__ void k_scan3(const int* __restrict__ indeg, const int* __restrict__ outdeg,
                        int n, const int* __restrict__ bsum,
                        int* __restrict__ row_start, float* __restrict__ dinv,
                        int* __restrict__ deg_i) {
  __shared__ int sc[1024];
  int tid = threadIdx.x;
  int i = blockIdx.x * 1024 + tid;
  int ind = (i < n) ? indeg[i] : 0;
  sc[tid] = ind;
  __syncthreads();
  for (int ofs = 1; ofs < 1024; ofs <<= 1) {
    int t = (tid >= ofs) ? sc[tid - ofs] : 0;
    __syncthreads();
    sc[tid] += t;
    __syncthreads();
  }
  if (i < n) {
    int incl = sc[tid];
    row_start[i] = incl - ind + bsum[blockIdx.x];
    dinv[i] = rsqrtf((float)ind + 1.0f);    // GCN deg = indeg + 1 (self loop)
    deg_i[i] = ind + outdeg[i];             // embedding degree = indeg + outdeg
  }
}

// ---------------- CSR fill: (src | deg<<20, coef) per edge ----------------
__global__ void k_fill(const int* __restrict__ ei, int E, const int* __restrict__ row_start,
                       int* __restrict__ cursor, const float* __restrict__ dinv,
                       const int* __restrict__ deg_i, int2* __restrict__ ec) {
  int e = blockIdx.x * blockDim.x + threadIdx.x;
  if (e >= E) return;
  int s = ei[e], d = ei[E + e];
  int pos = row_start[d] + atomicAdd(&cursor[d], 1);
  int dg = deg_i[s]; if (dg > 127) dg = 127;
  int2 v;
  v.x = s | (dg << 20);
  v.y = __float_as_int(dinv[s] * dinv[d]);
  ec[pos] = v;
}

// ---------------- Wv = Wfg(512x32) @ wg[64:96] (3 cols), fp32 ----------------
__global__ void k_wv(const float* __restrict__ Wfg, const float* __restrict__ bfg,
                     const float* __restrict__ wg, float* __restrict__ Wv4) {
  int k = blockIdx.x * blockDim.x + threadIdx.x;
  if (k >= 512) return;
  float a0 = 0.f, a1 = 0.f, a2 = 0.f;
  for (int j = 0; j < 32; ++j) {
    float w = Wfg[k * 32 + j];
    a0 += w * wg[(64 + j) * 3 + 0];
    a1 += w * wg[(64 + j) * 3 + 1];
    a2 += w * wg[(64 + j) * 3 + 2];
  }
  float4 v; v.x = a0; v.y = a1; v.z = a2; v.w = 0.f;
  *(float4*)&Wv4[k * 4] = v;
  if (k == 0) {
    float c0 = 0.f, c1 = 0.f, c2 = 0.f;
    for (int j = 0; j < 32; ++j) {
      float b = bfg[j];
      c0 += b * wg[(64 + j) * 3 + 0];
      c1 += b * wg[(64 + j) * 3 + 1];
      c2 += b * wg[(64 + j) * 3 + 2];
    }
    float4 c; c.x = c0; c.y = c1; c.z = c2; c.w = 0.f;
    *(float4*)&Wv4[512 * 4] = c;
  }
}

// ---------------- k_wb: [Wf0|Wf2] -> bf16 fragment-ordered Wb ----------------
__global__ void k_wb(const float* __restrict__ Wf0, const float* __restrict__ Wf2,
                     unsigned short* __restrict__ Wb) {
  int tid = blockIdx.x * blockDim.x + threadIdx.x;   // 4096 threads
  if (tid >= 16 * 4 * 64) return;
  int l = tid & 63;
  int nt = (tid >> 6) & 3;
  int ks = tid >> 8;
  int col = (nt << 4) + (l & 15);
  int rowb = ks * 32 + ((l >> 4) << 3);
  const float* wsrc = (col < 32) ? (Wf0 + col) : (Wf2 + (col - 32));
  unsigned short pb[8];
#pragma unroll
  for (int j = 0; j < 8; ++j)
    pb[j] = bf16u(wsrc[(size_t)(rowb + j) * 32]);
  *(uint4*)&Wb[(size_t)tid * 8] = *(const uint4*)pb;
}

// ---------------- k_projm: barrier-free bf16 MFMA + fused fp32 CFG + logits pack --------
__global__ __launch_bounds__(64) void k_projm(
    const float* __restrict__ feat,
    const unsigned short* __restrict__ Wb,
    const float* __restrict__ bf0, const float* __restrict__ bf2,
    const float* __restrict__ Wv4, const float* __restrict__ logits,
    unsigned* __restrict__ Xu, float* __restrict__ CFG, int n) {
  int l = threadIdx.x;
  int gw = blockIdx.x;
  int node_in = gw * 16 + (l & 15);
  int nc = node_in < n ? node_in : n - 1;
  const float* frow = feat + (size_t)nc * 512 + ((l >> 4) << 3);

  f32x4 acc[4];
#pragma unroll
  for (int q = 0; q < 4; ++q) acc[q] = (f32x4){0.f, 0.f, 0.f, 0.f};
  float cfg0 = 0.f, cfg1 = 0.f, cfg2 = 0.f;

  for (int ks = 0; ks < 16; ++ks) {
    float4 fa = *(const float4*)&frow[ks * 32];
    float4 fb = *(const float4*)&frow[ks * 32 + 4];
    float fv[8] = {fa.x, fa.y, fa.z, fa.w, fb.x, fb.y, fb.z, fb.w};
    const float* wvp = Wv4 + (ks * 32 + ((l >> 4) << 3)) * 4;
#pragma unroll
    for (int j = 0; j < 8; ++j) {
      float4 v = *(const float4*)&wvp[j * 4];
      cfg0 += fv[j] * v.x;
      cfg1 += fv[j] * v.y;
      cfg2 += fv[j] * v.z;
    }
    unsigned short pa[8];
#pragma unroll
    for (int j = 0; j < 8; ++j) pa[j] = bf16u(fv[j]);
    short8 af = *(const short8*)pa;
#pragma unroll
    for (int nt = 0; nt < 4; ++nt) {
      short8 bfv = *(const short8*)&Wb[(size_t)((ks * 4 + nt) * 64 + l) * 8];
      acc[nt] = __builtin_amdgcn_mfma_f32_16x16x32_bf16(af, bfv, acc[nt], 0, 0, 0);
    }
  }

  cfg0 += __shfl_xor(cfg0, 16); cfg0 += __shfl_xor(cfg0, 32);
  cfg1 += __shfl_xor(cfg1, 16); cfg1 += __shfl_xor(cfg1, 32);
  cfg2 += __shfl_xor(cfg2, 16); cfg2 += __shfl_xor(cfg2, 32);
  if (l < 16 && node_in < n) {
    float4 cc = *(const float4*)&Wv4[512 * 4];
    CFG[node_in] = cfg0 + cc.x;
    CFG[n + node_in] = cfg1 + cc.y;
    CFG[2 * (size_t)n + node_in] = cfg2 + cc.z;
  }

  unsigned short* Xus = (unsigned short*)Xu;
#pragma unroll
  for (int nt = 0; nt < 4; ++nt) {
    int col = (nt << 4) + (l & 15);
    float bias = (col < 32) ? bf0[col] : bf2[col - 32];
    int fidx = 64 + col;
#pragma unroll
    for (int r = 0; r < 4; ++r) {
      int nd = gw * 16 + ((l >> 4) << 2) + r;
      if (nd < n) Xus[(size_t)nd * 128 + fidx] = bf16u(acc[nt][r] + bias);
    }
  }

  // logits -> Xu bf16 pack for this wave's 16 nodes
  int nb16 = gw * 16;
#pragma unroll
  for (int q = 0; q < 8; ++q) {
    int ii = q * 64 + l;
    int nd = nb16 + (ii >> 5);
    int p = ii & 31;
    if (nd < n) {
      float2 lg = *(const float2*)&logits[(size_t)nd * 64 + 2 * p];
      Xu[(size_t)nd * 64 + p] = pk_bf16(lg.x, lg.y);
    }
  }
}

// ---------------- aggregation: Zt(bf16) = A_hat @ [Xu(256B rows) | Emb(packed deg)] ------
__global__ __launch_bounds__(256) void k_agg(
    const unsigned* __restrict__ Xu, unsigned* __restrict__ Ztu,
    const int* __restrict__ row_start, const int2* __restrict__ ec,
    const int* __restrict__ deg_i,
    const float* __restrict__ Emb1, const float* __restrict__ Emb2,
    const float* __restrict__ dinv, int n) {
  int w = threadIdx.x >> 6, l = threadIdx.x & 63;
  int node = blockIdx.x * 4 + w;
  if (node >= n) return;
  int beg = row_start[node], end = row_start[node + 1];

  const float* etab = (l < 8) ? (Emb1 + 2 * l) : (Emb2 + 2 * (l - 8));

  float ax = 0.f, ay = 0.f, bx = 0.f, by = 0.f;
  int i = beg;
  for (; i + 4 <= end; i += 4) {
    int2 e0 = ec[i];
    int2 e1 = ec[i + 1];
    int2 e2 = ec[i + 2];
    int2 e3 = ec[i + 3];
    unsigned u0 = Xu[(size_t)(e0.x & 0xFFFFF) * 64 + l];
    unsigned u1 = Xu[(size_t)(e1.x & 0xFFFFF) * 64 + l];
    unsigned u2 = Xu[(size_t)(e2.x & 0xFFFFF) * 64 + l];
    unsigned u3 = Xu[(size_t)(e3.x & 0xFFFFF) * 64 + l];
    float c0 = __int_as_float(e0.y);
    float c1 = __int_as_float(e1.y);
    float c2 = __int_as_float(e2.y);
    float c3 = __int_as_float(e3.y);
    ax += c0 * bf_lo(u0); ay += c0 * bf_hi(u0);
    ax += c1 * bf_lo(u1); ay += c1 * bf_hi(u1);
    ax += c2 * bf_lo(u2); ay += c2 * bf_hi(u2);
    ax += c3 * bf_lo(u3); ay += c3 * bf_hi(u3);
    if (l < 16) {
      float2 ev0 = *(const float2*)&etab[(e0.x >> 20) * 16];
      float2 ev1 = *(const float2*)&etab[(e1.x >> 20) * 16];
      float2 ev2 = *(const float2*)&etab[(e2.x >> 20) * 16];
      float2 ev3 = *(const float2*)&etab[(e3.x >> 20) * 16];
      bx += c0 * ev0.x; by += c0 * ev0.y;
      bx += c1 * ev1.x; by += c1 * ev1.y;
      bx += c2 * ev2.x; by += c2 * ev2.y;
      bx += c3 * ev3.x; by += c3 * ev3.y;
    }
  }
  for (; i < end; ++i) {
    int2 e0 = ec[i];
    int s0 = e0.x & 0xFFFFF;
    float c0 = __int_as_float(e0.y);
    unsigned u0 = Xu[(size_t)s0 * 64 + l];
    ax += c0 * bf_lo(u0); ay += c0 * bf_hi(u0);
    if (l < 16) {
      float2 ev0 = *(const float2*)&etab[(e0.x >> 20) * 16];
      bx += c0 * ev0.x; by += c0 * ev0.y;
    }
  }
  // self loop
  float di = dinv[node];
  float c2s = di * di;
  {
    unsigned u = Xu[(size_t)node * 64 + l];
    ax += c2s * bf_lo(u);
    ay += c2s * bf_hi(u);
    if (l < 16) {
      int dg = deg_i[node]; if (dg > 127) dg = 127;
      float2 ev = *(const float2*)&etab[dg * 16];
      bx += c2s * ev.x;
      by += c2s * ev.y;
    }
  }
  {
    int nf = 2 * l;
    int of = nf + (nf >= 96 ? 16 : 0);
    Ztu[2 * ((size_t)(of >> 2) * n + node) + ((of >> 1) & 1)] = pk_bf16(ax, ay);
  }
  if (l < 16) {
    int p = l & 7;
    int of = (l < 8) ? (96 + 2 * p) : (144 + 2 * p);
    Ztu[2 * ((size_t)(of >> 2) * n + node) + (p & 1)] = pk_bf16(bx, by);
  }
}

// ---------------- final: 4-way column split, 1 wave/block, comb[16] ----------------
__global__ __launch_bounds__(64) void k_final(
    const unsigned* __restrict__ Ztu, const float* __restrict__ logits,
    const float* __restrict__ CFG, const int* __restrict__ deg_i,
    const float* __restrict__ W0, const float* __restrict__ b0,
    const float* __restrict__ W1, const float* __restrict__ b1,
    const float* __restrict__ W2, const float* __restrict__ b2,
    const float* __restrict__ Embg, const float* __restrict__ wg,
    float* __restrict__ out, int n) {
  int l = threadIdx.x;
  int g = blockIdx.x >> 2;
  int cb = (blockIdx.x & 3) * 16;      // column base
  int node = g * 64 + l;
  int nc = node < n ? node : n - 1;

  float c0 = 0.f, c1 = 0.f, c2 = 0.f;
  const float* lgr = logits + (size_t)nc * 64;
#pragma unroll
  for (int q = 0; q < 16; ++q) {
    float4 v = *(const float4*)&lgr[q * 4];
    const float* p = (const float*)&v;
#pragma unroll
    for (int j = 0; j < 4; ++j) {
      int k = q * 4 + j;
      c0 += p[j] * wg[k * 3 + 0];
      c1 += p[j] * wg[k * 3 + 1];
      c2 += p[j] * wg[k * 3 + 2];
    }
  }
  {
    int dg = deg_i[nc]; if (dg > 127) dg = 127;
    const float* egr = Embg + dg * 16;
#pragma unroll
    for (int q = 0; q < 4; ++q) {
      float4 v = *(const float4*)&egr[q * 4];
      const float* p = (const float*)&v;
#pragma unroll
      for (int j = 0; j < 4; ++j) {
        int k = 96 + q * 4 + j;
        c0 += p[j] * wg[k * 3 + 0];
        c1 += p[j] * wg[k * 3 + 1];
        c2 += p[j] * wg[k * 3 + 2];
      }
    }
  }
  c0 += CFG[nc];
  c1 += CFG[n + nc];
  c2 += CFG[2 * (size_t)n + nc];

  int i0 = 0; float t0 = c0;
  if (c1 > t0) { t0 = c1; i0 = 1; }
  if (c2 > t0) { t0 = c2; i0 = 2; }
  float t1 = -3.4e38f; int i1 = 0;
  if (i0 != 0) { t1 = c0; i1 = 0; }
  if (i0 != 1 && c1 > t1) { t1 = c1; i1 = 1; }
  if (i0 != 2 && c2 > t1) { t1 = c2; i1 = 2; }
  float e1v = expf(t1 - t0);
  float gsum = 1.0f + e1v;
  float gA = 1.0f / gsum, gB = e1v / gsum;
  float g0 = (i0 == 0) ? gA : (i1 == 0) ? gB : 0.f;
  float g1 = (i0 == 1) ? gA : (i1 == 1) ? gB : 0.f;
  float g2 = (i0 == 2) ? gA : (i1 == 2) ? gB : 0.f;

  float comb[16];
#pragma unroll
  for (int c = 0; c < 16; ++c) comb[c] = 0.f;

#define CHUNK(CIDX, GE, WPTR, KROW)                                        \
  {                                                                        \
    uint2 zu = *(const uint2*)&Ztu[2 * ((size_t)(CIDX) * n + nc)];         \
    float zs[4] = {(GE) * bf_lo(zu.x), (GE) * bf_hi(zu.x),                 \
                   (GE) * bf_lo(zu.y), (GE) * bf_hi(zu.y)};                \
    const float* wr = (WPTR) + (KROW) * 64 + cb;                           \
    _Pragma("unroll") for (int kk = 0; kk < 4; ++kk) {                     \
      float zz = zs[kk];                                                   \
      const float* wrow = wr + kk * 64;                                    \
      _Pragma("unroll") for (int c = 0; c < 16; ++c)                       \
        comb[c] += zz * wrow[c];                                           \
    }                                                                      \
  }

  for (int t = 0; t < 24; ++t) CHUNK(t, g0, W0, 4 * t);
  for (int t = 0; t < 16; ++t) CHUNK(t, g1, W1, 4 * t);
  for (int t = 0; t < 4; ++t)  CHUNK(24 + t, g1, W1, 64 + 4 * t);
  for (int t = 0; t < 12; ++t) CHUNK(28 + t, g2, W2, 4 * t);
#undef CHUNK

#pragma unroll
  for (int c = 0; c < 16; ++c)
    comb[c] += g0 * b0[cb + c] + g1 * b1[cb + c] + g2 * b2[cb + c];

  if (node < n) {
    float* outr = out + (size_t)node * 64 + cb;
#pragma unroll
    for (int q = 0; q < 4; ++q) {
      float4 lg4 = *(const float4*)&lgr[cb + q * 4];
      const float* pl = (const float*)&lg4;
      float4 o;
      float* po = (float*)&o;
#pragma unroll
      for (int j = 0; j < 4; ++j) {
        float v = comb[q * 4 + j];
        float sp = fmaxf(v, 0.f) + log1pf(expf(-fabsf(v)));
        po[j] = pl[j] * sp;
      }
      *(float4*)&outr[q * 4] = o;
    }
  }
}

extern "C" void kernel_launch(void* const* d_in, const int* in_sizes, int n_in,
                              void* d_out, int out_size, void* d_ws, size_t ws_size,
                              hipStream_t stream) {
  const float* logits = (const float*)d_in[0];
  const float* feat   = (const float*)d_in[1];
  const int*   ei     = (const int*)d_in[2];
  const float* Wf0 = (const float*)d_in[3];
  const float* bf0 = (const float*)d_in[4];
  const float* W0  = (const float*)d_in[5];
  const float* b0  = (const float*)d_in[6];
  const float* Emb1= (const float*)d_in[7];
  const float* W1  = (const float*)d_in[8];
  const float* b1  = (const float*)d_in[9];
  const float* Wf2 = (const float*)d_in[10];
  const float* bf2 = (const float*)d_in[11];
  const float* Emb2= (const float*)d_in[12];
  const float* W2  = (const float*)d_in[13];
  const float* b2  = (const float*)d_in[14];
  const float* Wfg = (const float*)d_in[15];
  const float* bfg = (const float*)d_in[16];
  const float* Embg= (const float*)d_in[17];
  const float* wg  = (const float*)d_in[18];

  int n = in_sizes[0] / 64;
  int E = in_sizes[2] / 2;
  int E2 = 2 * E;
  int nbk = (n + 511) / 512;           // buckets per stream (<=256 for n<=131072)
  int nb2 = 2 * nbk;

  char* base = (char*)d_ws;
  size_t off = 0;
  auto alloc = [&](size_t bytes) -> void* {
    void* p = base + off;
    off += bytes;
    off = (off + 255) & ~(size_t)255;
    return p;
  };
  unsigned* bucketTotal = (unsigned*)alloc((size_t)nb2 * 4);
  int*   cursor    = (int*)alloc((size_t)n * 4);
  size_t zero_bytes = off;                 // bucketTotal + cursor
  unsigned* bucketOffset = (unsigned*)alloc(((size_t)nb2 + 1) * 4);
  unsigned* bucketCursor = (unsigned*)alloc((size_t)nb2 * 4);
  int*   partIds   = (int*)alloc((size_t)E2 * 4);
  int*   indeg     = (int*)alloc((size_t)n * 4);
  int*   outdeg    = (int*)alloc((size_t)n * 4);
  int*   deg_i     = (int*)alloc((size_t)n * 4);
  int*   row_start = (int*)alloc(((size_t)n + 1) * 4);
  int*   bsum      = (int*)alloc(1024 * 4);
  float* dinv      = (float*)alloc((size_t)n * 4);
  int2*  ec        = (int2*)alloc((size_t)E * 8);
  float* CFG       = (float*)alloc((size_t)n * 3 * 4);
  float* Wv4       = (float*)alloc((size_t)513 * 4 * 4);
  unsigned short* Wb = (unsigned short*)alloc((size_t)16 * 4 * 64 * 8 * 2);  // 64KB
  unsigned* Xu     = (unsigned*)alloc((size_t)n * 64 * 4);   // bf16 X: 128 feat x 2B
  unsigned* Ztu    = (unsigned*)alloc((size_t)n * 80 * 4);   // bf16 Zt (160 feat)
  (void)ws_size;

  hipMemsetAsync(base, 0, zero_bytes, stream);

  int nb_scan = (n + 1023) / 1024;
  int nblk_ids = (E2 + 4095) / 4096;
  k_wv<<<2, 256, 0, stream>>>(Wfg, bfg, wg, Wv4);
  k_wb<<<16, 256, 0, stream>>>(Wf0, Wf2, Wb);
  k_h0<<<nblk_ids, 256, 0, stream>>>(ei, E2, E, nbk, bucketTotal);
  k_hs<<<1, 64, 0, stream>>>(bucketTotal, nb2, bucketOffset, bucketCursor);
  k_hb<<<nblk_ids, 256, 0, stream>>>(ei, E2, E, nbk, bucketCursor, partIds);
  k_h3<<<nb2, 256, 0, stream>>>(partIds, bucketOffset, nbk, n, indeg, outdeg);
  k_projm<<<(n + 15) / 16, 64, 0, stream>>>(feat, Wb, bf0, bf2, Wv4, logits, Xu, CFG, n);
  k_scan1<<<nb_scan, 1024, 0, stream>>>(indeg, n, bsum);
  k_scan2<<<1, 64, 0, stream>>>(bsum, nb_scan, row_start, n);
  k_scan3<<<nb_scan, 1024, 0, stream>>>(indeg, outdeg, n, bsum, row_start, dinv, deg_i);
  k_fill<<<(E + 255) / 256, 256, 0, stream>>>(ei, E, row_start, cursor, dinv, deg_i, ec);
  k_agg<<<(n + 3) / 4, 256, 0, stream>>>(Xu, Ztu, row_start, ec, deg_i, Emb1, Emb2, dinv, n);
  int waves = (n + 63) / 64;
  k_final<<<waves * 4, 64, 0, stream>>>(Ztu, logits, CFG, deg_i, W0, b0, W1, b1, W2, b2,
                                        Embg, wg, (float*)d_out, n);
}